// Round 5
// baseline (122.192 us; speedup 1.0000x reference)
//
#include <hip/hip_runtime.h>
#include <hip/hip_bf16.h>
#include <math.h>

// B=16, H=64, W=64, C=64 -> N=4096 pixels/batch, M=1024 pooled cells.
#define NB 16
#define NPIX 4096
#define MPOOL 1024

typedef __attribute__((ext_vector_type(8))) short bf16x8;    // 8 bf16 (4 VGPRs)
typedef __attribute__((ext_vector_type(4))) float f32x4;     // 16x16 MFMA C/D
typedef __attribute__((ext_vector_type(16))) float f32x16;   // 32x32 MFMA C/D

#define LOG2E 1.44269504088896340736f

__device__ inline unsigned short f2bf(float f) {
    __hip_bfloat16 h = __float2bfloat16(f);
    return *reinterpret_cast<unsigned short*>(&h);
}

#if defined(__has_builtin)
#if __has_builtin(__builtin_amdgcn_cvt_pk_bf16_f32)
#define HAVE_PK_BF16 1
#endif
#endif
__device__ inline unsigned pack_bf16(float a, float b) {
#ifdef HAVE_PK_BF16
    typedef __bf16 bf16v2 __attribute__((ext_vector_type(2)));
    bf16v2 v = __builtin_amdgcn_cvt_pk_bf16_f32(a, b);
    unsigned u;
    __builtin_memcpy(&u, &v, 4);
    return u;
#else
    unsigned ua = __float_as_uint(a) + 0x8000u;
    unsigned ub = __float_as_uint(b) + 0x8000u;
    return __builtin_amdgcn_perm(ua, ub, 0x03020706u);
#endif
}

// Workspace layout (u16 elements from start of ws):
//   theta_bf @0        [16*4096*8]   (PRE-SCALED by log2e for exp2-softmax)
//   phi_bf   @524288   [16*1024*8]
//   gT_bf    @655360   [16*32*1024]
//   woT_bf   @1179648  [64*32]       (SN'd w_o, transposed [co][k])

__device__ inline float wave_sum64(float v) {
    #pragma unroll
    for (int off = 32; off >= 1; off >>= 1) v += __shfl_xor(v, off);
    return v;
}

// Wave-local spectral norm (one power-iteration step, matches reference).
// Whole wave must enter. Returns 1/sigma (wave-uniform).
template<int D, int COUT>
__device__ float sn_inv_sigma(const float* __restrict__ w, const float* __restrict__ u) {
    const int lane = threadIdx.x & 63;
    float vi = 0.f;
    if (lane < D) {
        #pragma unroll 8
        for (int j = 0; j < COUT; ++j) vi += w[lane * COUT + j] * u[j];
    }
    float nn = wave_sum64(vi * vi);
    vi *= 1.0f / (sqrtf(nn) + 1e-12f);

    float u2 = 0.f;
    #pragma unroll 8
    for (int i = 0; i < D; ++i) {
        float vv = __shfl(vi, i);                   // all lanes execute the shuffle
        if (lane < COUT) u2 += w[i * COUT + lane] * vv;
    }
    float nn2 = wave_sum64(u2 * u2);
    u2 *= 1.0f / (sqrtf(nn2) + 1e-12f);

    float ti = 0.f;
    #pragma unroll 8
    for (int j = 0; j < COUT; ++j) {
        float uv = __shfl(u2, j);
        if (lane < D) ti += w[lane * COUT + j] * uv;
    }
    float sig = wave_sum64(vi * ti);
    return 1.0f / sig;
}

// ---------------- fused SN + conv: theta + (phi,g)+maxpool via MFMA ----------------
// (byte-identical to the verified round-3 kernel)
__global__ __launch_bounds__(256) void conv_all_kernel(const float* __restrict__ x,
                                                       const float* __restrict__ w_theta, const float* __restrict__ u_theta,
                                                       const float* __restrict__ w_phi,   const float* __restrict__ u_phi,
                                                       const float* __restrict__ w_g,     const float* __restrict__ u_g,
                                                       const float* __restrict__ w_o,     const float* __restrict__ u_o,
                                                       unsigned short* __restrict__ theta_bf,
                                                       unsigned short* __restrict__ phi_bf,
                                                       unsigned short* __restrict__ gT_bf,
                                                       unsigned short* __restrict__ woT_bf) {
    __shared__ unsigned short sx[128 * 72];  // x strip bf16, row pad 72 (reused for out-staging)
    __shared__ unsigned short sw[48 * 72];   // W^T [col][k], pad 72
    __shared__ float s_inv[3];

    const int tid  = threadIdx.x;
    const int b    = blockIdx.x >> 5;
    const int hp   = blockIdx.x & 31;        // rows 2hp, 2hp+1
    const int h0   = hp * 2;
    const int wv   = tid >> 6;
    const int lane = tid & 63;
    const int quad = lane >> 4;
    const int lcol = lane & 15;
    const int w0   = wv * 16;

    // stage x strip: 8192 floats = 2048 float4 -> 8 iters
    const float4* xb4 = (const float4*)(x + (((size_t)b * NPIX) + h0 * 64) * 64);
    #pragma unroll
    for (int it = 0; it < 8; ++it) {
        const int li = tid + it * 256;
        float4 v = xb4[li];
        const int px = li >> 4, c4 = li & 15;
        uint2 pk;
        pk.x = pack_bf16(v.x, v.y);
        pk.y = pack_bf16(v.z, v.w);
        *(uint2*)(&sx[px * 72 + c4 * 4]) = pk;
    }
    // per-wave spectral norm (redundant across blocks; weights tiny + L2-hot)
    if (wv == 0)      { float iv = sn_inv_sigma<64, 8>(w_theta, u_theta); if (lane == 0) s_inv[0] = iv; }
    else if (wv == 1) { float iv = sn_inv_sigma<64, 8>(w_phi,   u_phi);   if (lane == 0) s_inv[1] = iv; }
    else if (wv == 2) { float iv = sn_inv_sigma<64, 32>(w_g,    u_g);     if (lane == 0) s_inv[2] = iv; }
    else if (blockIdx.x == 0) {
        // block 0 wave 3: w_o spectral norm -> woT_bf[n*32+k] = bf16(w_o[k][n]/sigma)
        float iv = sn_inv_sigma<32, 64>(w_o, u_o);
        for (int idx = lane; idx < 64 * 32; idx += 64) {
            const int n = idx >> 5, k = idx & 31;
            woT_bf[idx] = f2bf(w_o[k * 64 + n] * iv);
        }
    }
    __syncthreads();

    // fill sw: cols 0-7 theta, 8-15 phi, 16-47 g; sw[col][k] = bf16(w[k][col]/sigma)
    {
        const float i0 = s_inv[0], i1 = s_inv[1], i2 = s_inv[2];
        #pragma unroll
        for (int it = 0; it < 12; ++it) {
            const int idx = tid + it * 256;      // 0..3071; col is wave-uniform per iter
            const int col = idx >> 6, k = idx & 63;
            float wvf, inv;
            if (col < 8)       { wvf = w_theta[k * 8 + col];        inv = i0; }
            else if (col < 16) { wvf = w_phi[k * 8 + (col - 8)];    inv = i1; }
            else               { wvf = w_g[k * 32 + (col - 16)];    inv = i2; }
            sw[col * 72 + k] = f2bf(wvf * inv);
        }
    }
    __syncthreads();

    bf16x8 a[2][2];
    #pragma unroll
    for (int hh = 0; hh < 2; ++hh)
        #pragma unroll
        for (int kc = 0; kc < 2; ++kc)
            a[hh][kc] = *(const bf16x8*)(sx + (hh * 64 + w0 + lcol) * 72 + kc * 32 + quad * 8);

    f32x4 acc[2][3];
    #pragma unroll
    for (int ct = 0; ct < 3; ++ct) {
        bf16x8 b0 = *(const bf16x8*)(sw + (ct * 16 + lcol) * 72 + 0 * 32 + quad * 8);
        bf16x8 b1 = *(const bf16x8*)(sw + (ct * 16 + lcol) * 72 + 1 * 32 + quad * 8);
        #pragma unroll
        for (int hh = 0; hh < 2; ++hh) {
            f32x4 c = __builtin_amdgcn_mfma_f32_16x16x32_bf16(a[hh][0], b0, (f32x4)0.0f, 0, 0, 0);
            acc[hh][ct] = __builtin_amdgcn_mfma_f32_16x16x32_bf16(a[hh][1], b1, c, 0, 0, 0);
        }
    }
    __syncthreads();   // all LDS reads of sx/sw done -> safe to overlay staging tiles

    // ---- stage outputs in LDS (overlaid on sx), then write coalesced ----
    unsigned short* th = sx;
    unsigned short* ph = sx + 1024;
    unsigned short* gg = sx + 1280;
    const int ml = (w0 >> 1) + quad * 2;     // local pooled m within block, 0..31
    if (lcol < 8) {
        #pragma unroll
        for (int hh = 0; hh < 2; ++hh) {
            const int pix = hh * 64 + w0 + quad * 4;
            #pragma unroll
            for (int r = 0; r < 4; ++r)
                th[(pix + r) * 8 + lcol] = f2bf(acc[hh][0][r] * LOG2E);  // pre-scale for exp2
        }
    } else {
        #pragma unroll
        for (int r2 = 0; r2 < 2; ++r2) {
            float pe = fmaxf(fmaxf(acc[0][0][2 * r2], acc[0][0][2 * r2 + 1]),
                             fmaxf(acc[1][0][2 * r2], acc[1][0][2 * r2 + 1]));
            ph[(ml + r2) * 8 + (lcol - 8)] = f2bf(pe);
        }
    }
    #pragma unroll
    for (int ct = 1; ct < 3; ++ct) {
        const int cg = (ct - 1) * 16 + lcol;
        #pragma unroll
        for (int r2 = 0; r2 < 2; ++r2) {
            float pe = fmaxf(fmaxf(acc[0][ct][2 * r2], acc[0][ct][2 * r2 + 1]),
                             fmaxf(acc[1][ct][2 * r2], acc[1][ct][2 * r2 + 1]));
            gg[cg * 32 + ml + r2] = f2bf(pe);
        }
    }
    __syncthreads();

    // coalesced global writes: 288 float4 total (th 128, ph 32, gg 128)
    const float4* sv4 = (const float4*)sx;
    float4* th4 = (float4*)(theta_bf + ((size_t)b * NPIX + hp * 128) * 8);
    float4* ph4 = (float4*)(phi_bf + ((size_t)b * MPOOL + hp * 32) * 8);
    for (int idx = tid; idx < 288; idx += 256) {
        float4 v = sv4[idx];
        if (idx < 128) {
            th4[idx] = v;
        } else if (idx < 160) {
            ph4[idx - 128] = v;
        } else {
            const int gi = idx - 160;            // 0..127
            const int ch = gi >> 2, part = gi & 3;
            *(float4*)(gT_bf + ((size_t)b * 32 + ch) * MPOOL + hp * 32 + part * 8) = v;
        }
    }
}

// ---------------- attn v2: 32x32 MFMA, P in registers via permlane32_swap ----------------
// Grid = 256 blocks (16 b x 16 qb) x 512 thr = 8 waves; wave = 32 q rows; 1 block/CU.
// All of phi (16KB) + gT (66KB padded) + woT staged ONCE; main loop is barrier-free:
//   per 32-m tile: S = mfma32x32(phi, theta)  [D: row=m, col=q=lane&31]
//   exp2 -> 16 e's -> 8 packed bf16 dwords -> 4 v_permlane32_swap_b32 give the PV
//   A-fragments in-register (no LDS round-trip, no lgkmcnt(0) serialization)
//   -> 2 PV mfma32x32 accumulate D[q][ch].
// Epilogue: per-wave LDS transpose [q][ch], out-conv 32x32 MFMAs, residual float4 stores.
__global__ __launch_bounds__(512) void attn_kernel(const unsigned short* __restrict__ theta_bf,
                                                   const unsigned short* __restrict__ phi_bf,
                                                   const unsigned short* __restrict__ gT_bf,
                                                   const unsigned short* __restrict__ woT_bf,
                                                   const float* __restrict__ x,
                                                   const float* __restrict__ gamma,
                                                   float* __restrict__ out) {
    __shared__ unsigned short sphi[MPOOL * 8];     // 16 KB   [m][k0..7]
    __shared__ unsigned short sg[32][1032];        // 66 KB   [ch][m], pad 8 (bank spread)
    __shared__ unsigned short swo[64 * 40];        // 5 KB    [co][k], pad 8
    __shared__ unsigned short strans[8][32 * 40];  // 20 KB   per-wave [q][ch], pad 8

    const int tid  = threadIdx.x;
    const int b    = blockIdx.x >> 4;
    const int qb   = blockIdx.x & 15;
    const int wv   = tid >> 6;
    const int lane = tid & 63;
    const int l31  = lane & 31;
    const int half = lane >> 5;

    // stage phi[b]: 1024 float4 over 512 thr
    {
        const float4* src = (const float4*)(phi_bf + (size_t)b * (MPOOL * 8));
        float4* dst = (float4*)sphi;
        dst[2 * tid]     = src[2 * tid];
        dst[2 * tid + 1] = src[2 * tid + 1];
    }
    // stage woT: 2048 u16 = 512 uint2
    {
        const int n = tid >> 3, ks = (tid & 7) * 4;
        *(uint2*)(swo + n * 40 + ks) = *(const uint2*)(woT_bf + n * 32 + ks);
    }
    // stage gT[b]: 32 rows x 128 float4; thread (r=tid>>4, seg=tid&15) copies m seg*64..+63
    {
        const unsigned short* gTb = gT_bf + (size_t)b * (32 * MPOOL);
        const int r = tid >> 4, seg = tid & 15;
        const float4* src = (const float4*)(gTb + r * MPOOL + seg * 64);
        float4* dst = (float4*)(&sg[r][seg * 64]);
        #pragma unroll
        for (int j = 0; j < 8; ++j) dst[j] = src[j];
    }
    // theta frag: B operand of 32x32x16 (col=q=lane&31, k-slice=half*8).
    // Lower half holds real k=0..7 (pre-scaled by log2e); upper half ZERO so the
    // garbage phi k>=8 A-slices contribute exactly 0.
    const int q0w = qb * 256 + wv * 32;
    bf16x8 tfrag = (bf16x8)(short)0;
    if (half == 0)
        tfrag = *(const bf16x8*)(theta_bf + ((size_t)b * NPIX + q0w + l31) * 8);
    __syncthreads();

    f32x16 acc = (f32x16)0.0f;   // D[q rows][ch=lane&31]
    float ls = 0.f;

    for (int mt = 0; mt < 32; ++mt) {
        const int m0 = mt * 32;
        // A = phi[32 m][16 k]: row=m0+lane&31; both halves read the same row (upper x0)
        bf16x8 pa = *(const bf16x8*)(sphi + (size_t)(m0 + l31) * 8);
        f32x16 S = __builtin_amdgcn_mfma_f32_32x32x16_bf16(pa, tfrag, (f32x16)0.0f, 0, 0, 0);
        // S layout: col=q=lane&31, row m = m0 + (reg&3) + 8*(reg>>2) + 4*half
        float e0  = exp2f(S[0]),  e1  = exp2f(S[1]),  e2  = exp2f(S[2]),  e3  = exp2f(S[3]);
        float e4  = exp2f(S[4]),  e5  = exp2f(S[5]),  e6  = exp2f(S[6]),  e7  = exp2f(S[7]);
        float e8  = exp2f(S[8]),  e9  = exp2f(S[9]),  e10 = exp2f(S[10]), e11 = exp2f(S[11]);
        float e12 = exp2f(S[12]), e13 = exp2f(S[13]), e14 = exp2f(S[14]), e15 = exp2f(S[15]);
        ls += (((e0 + e1) + (e2 + e3)) + ((e4 + e5) + (e6 + e7)))
            + (((e8 + e9) + (e10 + e11)) + ((e12 + e13) + (e14 + e15)));
        unsigned c0 = pack_bf16(e0, e1),   c1 = pack_bf16(e2, e3);
        unsigned c2 = pack_bf16(e4, e5),   c3 = pack_bf16(e6, e7);
        unsigned c4 = pack_bf16(e8, e9),   c5 = pack_bf16(e10, e11);
        unsigned c6 = pack_bf16(e12, e13), c7 = pack_bf16(e14, e15);
        // Half-exchange: after swap(cHI,cLO): cHI = d2 (all lanes), cLO = d0 (all lanes).
        asm("v_permlane32_swap_b32 %0, %1" : "+v"(c2), "+v"(c0));
        asm("v_permlane32_swap_b32 %0, %1" : "+v"(c3), "+v"(c1));
        asm("v_permlane32_swap_b32 %0, %1" : "+v"(c6), "+v"(c4));
        asm("v_permlane32_swap_b32 %0, %1" : "+v"(c7), "+v"(c5));
        // PV chunk 0: m = m0..m0+15.  A[q][m]: lane supplies k = half*8 + 0..7.
        unsigned f0[4] = {c0, c1, c2, c3};
        bf16x8 p0; __builtin_memcpy(&p0, f0, 16);
        bf16x8 gb0 = *(const bf16x8*)(&sg[l31][m0 + half * 8]);
        acc = __builtin_amdgcn_mfma_f32_32x32x16_bf16(p0, gb0, acc, 0, 0, 0);
        // PV chunk 1: m = m0+16..m0+31
        unsigned f1[4] = {c4, c5, c6, c7};
        bf16x8 p1; __builtin_memcpy(&p1, f1, 16);
        bf16x8 gb1 = *(const bf16x8*)(&sg[l31][m0 + 16 + half * 8]);
        acc = __builtin_amdgcn_mfma_f32_32x32x16_bf16(p1, gb1, acc, 0, 0, 0);
    }

    // softmax denominator for q=lane&31: lanes l and l+32 hold disjoint m-subsets
    ls += __shfl_xor(ls, 32);
    const float invq = 1.0f / ls;

    // per-wave transpose: acc (ch=lane&31, 16 q-rows) -> strans[q][ch]  (UNNORMALIZED)
    unsigned short* st = &strans[wv][0];
    #pragma unroll
    for (int r = 0; r < 16; ++r) {
        const int q = (r & 3) + 8 * (r >> 2) + 4 * half;
        st[q * 40 + l31] = f2bf(acc[r]);
    }
    asm volatile("s_waitcnt lgkmcnt(0)" ::: "memory");

    const float gmi = gamma[0] * invq;
    const size_t pixbase = ((size_t)b * NPIX + q0w + l31) * 64;
    #pragma unroll
    for (int ct = 0; ct < 2; ++ct) {           // co tiles 0-31, 32-63
        f32x16 oc = (f32x16)0.0f;
        #pragma unroll
        for (int kc = 0; kc < 2; ++kc) {       // k = ch chunks 0-15, 16-31
            bf16x8 wa = *(const bf16x8*)(swo + (ct * 32 + l31) * 40 + kc * 16 + half * 8);
            bf16x8 ag = *(const bf16x8*)(st + l31 * 40 + kc * 16 + half * 8);
            oc = __builtin_amdgcn_mfma_f32_32x32x16_bf16(wa, ag, oc, 0, 0, 0);
        }
        // D[co][q]: col=q=lane&31, row co = ct*32 + (reg&3) + 8*(reg>>2) + 4*half
        #pragma unroll
        for (int r2 = 0; r2 < 4; ++r2) {
            const int co = ct * 32 + 8 * r2 + 4 * half;
            const float4 xv = *(const float4*)(x + pixbase + co);
            float4 ov;
            ov.x = xv.x + gmi * oc[4 * r2 + 0];
            ov.y = xv.y + gmi * oc[4 * r2 + 1];
            ov.z = xv.z + gmi * oc[4 * r2 + 2];
            ov.w = xv.w + gmi * oc[4 * r2 + 3];
            *(float4*)(out + pixbase + co) = ov;
        }
    }
}

extern "C" void kernel_launch(void* const* d_in, const int* in_sizes, int n_in,
                              void* d_out, int out_size, void* d_ws, size_t ws_size,
                              hipStream_t stream) {
    const float* x       = (const float*)d_in[0];
    const float* w_theta = (const float*)d_in[1];
    const float* u_theta = (const float*)d_in[2];
    const float* w_phi   = (const float*)d_in[3];
    const float* u_phi   = (const float*)d_in[4];
    const float* w_g     = (const float*)d_in[5];
    const float* u_g     = (const float*)d_in[6];
    const float* w_o     = (const float*)d_in[7];
    const float* u_o     = (const float*)d_in[8];
    const float* gamma   = (const float*)d_in[9];
    float* out = (float*)d_out;

    unsigned short* u16base  = (unsigned short*)d_ws;
    unsigned short* theta_bf = u16base;                  // 524288
    unsigned short* phi_bf   = u16base + 524288;         // 131072
    unsigned short* gT_bf    = u16base + 655360;         // 524288
    unsigned short* woT_bf   = u16base + 1179648;        // 2048

    conv_all_kernel<<<512, 256, 0, stream>>>(x, w_theta, u_theta, w_phi, u_phi, w_g, u_g,
                                             w_o, u_o, theta_bf, phi_bf, gT_bf, woT_bf);
    attn_kernel<<<256, 512, 0, stream>>>(theta_bf, phi_bf, gT_bf, woT_bf, x, gamma, out);
}

// Round 6
// 120.116 us; speedup vs baseline: 1.0173x; 1.0173x over previous
//
#include <hip/hip_runtime.h>
#include <hip/hip_bf16.h>
#include <math.h>

// B=16, H=64, W=64, C=64 -> N=4096 pixels/batch, M=1024 pooled cells.
#define NB 16
#define NPIX 4096
#define MPOOL 1024

typedef __attribute__((ext_vector_type(8))) short bf16x8;  // 8 bf16 (4 VGPRs)
typedef __attribute__((ext_vector_type(4))) float f32x4;   // MFMA C/D frag

#define LOG2E 1.44269504088896340736f

__device__ inline unsigned short f2bf(float f) {
    __hip_bfloat16 h = __float2bfloat16(f);
    return *reinterpret_cast<unsigned short*>(&h);
}

#if defined(__has_builtin)
#if __has_builtin(__builtin_amdgcn_cvt_pk_bf16_f32)
#define HAVE_PK_BF16 1
#endif
#endif
__device__ inline unsigned pack_bf16(float a, float b) {
#ifdef HAVE_PK_BF16
    typedef __bf16 bf16v2 __attribute__((ext_vector_type(2)));
    bf16v2 v = __builtin_amdgcn_cvt_pk_bf16_f32(a, b);
    unsigned u;
    __builtin_memcpy(&u, &v, 4);
    return u;
#else
    unsigned ua = __float_as_uint(a) + 0x8000u;
    unsigned ub = __float_as_uint(b) + 0x8000u;
    return __builtin_amdgcn_perm(ua, ub, 0x03020706u);
#endif
}

// Workspace layout (u16 elements from start of ws):
//   theta_bf @0        [16*4096*8]   (PRE-SCALED by log2e for exp2-softmax)
//   phi_bf   @524288   [16*1024*8]
//   gT_bf    @655360   [16*32*1024]
//   woT_bf   @1179648  [64*32]       (SN'd w_o, transposed [co][k])

__device__ inline float wave_sum64(float v) {
    #pragma unroll
    for (int off = 32; off >= 1; off >>= 1) v += __shfl_xor(v, off);
    return v;
}

// Wave-local spectral norm (one power-iteration step, matches reference).
// Whole wave must enter. Returns 1/sigma (wave-uniform).
template<int D, int COUT>
__device__ float sn_inv_sigma(const float* __restrict__ w, const float* __restrict__ u) {
    const int lane = threadIdx.x & 63;
    float vi = 0.f;
    if (lane < D) {
        #pragma unroll 8
        for (int j = 0; j < COUT; ++j) vi += w[lane * COUT + j] * u[j];
    }
    float nn = wave_sum64(vi * vi);
    vi *= 1.0f / (sqrtf(nn) + 1e-12f);

    float u2 = 0.f;
    #pragma unroll 8
    for (int i = 0; i < D; ++i) {
        float vv = __shfl(vi, i);                   // all lanes execute the shuffle
        if (lane < COUT) u2 += w[i * COUT + lane] * vv;
    }
    float nn2 = wave_sum64(u2 * u2);
    u2 *= 1.0f / (sqrtf(nn2) + 1e-12f);

    float ti = 0.f;
    #pragma unroll 8
    for (int j = 0; j < COUT; ++j) {
        float uv = __shfl(u2, j);
        if (lane < D) ti += w[lane * COUT + j] * uv;
    }
    float sig = wave_sum64(vi * ti);
    return 1.0f / sig;
}

// ---------------- fused SN + conv: theta + (phi,g)+maxpool via MFMA ----------------
// (byte-identical to the verified round-3 kernel — control variable)
__global__ __launch_bounds__(256) void conv_all_kernel(const float* __restrict__ x,
                                                       const float* __restrict__ w_theta, const float* __restrict__ u_theta,
                                                       const float* __restrict__ w_phi,   const float* __restrict__ u_phi,
                                                       const float* __restrict__ w_g,     const float* __restrict__ u_g,
                                                       const float* __restrict__ w_o,     const float* __restrict__ u_o,
                                                       unsigned short* __restrict__ theta_bf,
                                                       unsigned short* __restrict__ phi_bf,
                                                       unsigned short* __restrict__ gT_bf,
                                                       unsigned short* __restrict__ woT_bf) {
    __shared__ unsigned short sx[128 * 72];  // x strip bf16, row pad 72 (reused for out-staging)
    __shared__ unsigned short sw[48 * 72];   // W^T [col][k], pad 72
    __shared__ float s_inv[3];

    const int tid  = threadIdx.x;
    const int b    = blockIdx.x >> 5;
    const int hp   = blockIdx.x & 31;        // rows 2hp, 2hp+1
    const int h0   = hp * 2;
    const int wv   = tid >> 6;
    const int lane = tid & 63;
    const int quad = lane >> 4;
    const int lcol = lane & 15;
    const int w0   = wv * 16;

    // stage x strip: 8192 floats = 2048 float4 -> 8 iters
    const float4* xb4 = (const float4*)(x + (((size_t)b * NPIX) + h0 * 64) * 64);
    #pragma unroll
    for (int it = 0; it < 8; ++it) {
        const int li = tid + it * 256;
        float4 v = xb4[li];
        const int px = li >> 4, c4 = li & 15;
        uint2 pk;
        pk.x = pack_bf16(v.x, v.y);
        pk.y = pack_bf16(v.z, v.w);
        *(uint2*)(&sx[px * 72 + c4 * 4]) = pk;
    }
    // per-wave spectral norm (redundant across blocks; weights tiny + L2-hot)
    if (wv == 0)      { float iv = sn_inv_sigma<64, 8>(w_theta, u_theta); if (lane == 0) s_inv[0] = iv; }
    else if (wv == 1) { float iv = sn_inv_sigma<64, 8>(w_phi,   u_phi);   if (lane == 0) s_inv[1] = iv; }
    else if (wv == 2) { float iv = sn_inv_sigma<64, 32>(w_g,    u_g);     if (lane == 0) s_inv[2] = iv; }
    else if (blockIdx.x == 0) {
        // block 0 wave 3: w_o spectral norm -> woT_bf[n*32+k] = bf16(w_o[k][n]/sigma)
        float iv = sn_inv_sigma<32, 64>(w_o, u_o);
        for (int idx = lane; idx < 64 * 32; idx += 64) {
            const int n = idx >> 5, k = idx & 31;
            woT_bf[idx] = f2bf(w_o[k * 64 + n] * iv);
        }
    }
    __syncthreads();

    // fill sw: cols 0-7 theta, 8-15 phi, 16-47 g; sw[col][k] = bf16(w[k][col]/sigma)
    {
        const float i0 = s_inv[0], i1 = s_inv[1], i2 = s_inv[2];
        #pragma unroll
        for (int it = 0; it < 12; ++it) {
            const int idx = tid + it * 256;      // 0..3071; col is wave-uniform per iter
            const int col = idx >> 6, k = idx & 63;
            float wvf, inv;
            if (col < 8)       { wvf = w_theta[k * 8 + col];        inv = i0; }
            else if (col < 16) { wvf = w_phi[k * 8 + (col - 8)];    inv = i1; }
            else               { wvf = w_g[k * 32 + (col - 16)];    inv = i2; }
            sw[col * 72 + k] = f2bf(wvf * inv);
        }
    }
    __syncthreads();

    bf16x8 a[2][2];
    #pragma unroll
    for (int hh = 0; hh < 2; ++hh)
        #pragma unroll
        for (int kc = 0; kc < 2; ++kc)
            a[hh][kc] = *(const bf16x8*)(sx + (hh * 64 + w0 + lcol) * 72 + kc * 32 + quad * 8);

    f32x4 acc[2][3];
    #pragma unroll
    for (int ct = 0; ct < 3; ++ct) {
        bf16x8 b0 = *(const bf16x8*)(sw + (ct * 16 + lcol) * 72 + 0 * 32 + quad * 8);
        bf16x8 b1 = *(const bf16x8*)(sw + (ct * 16 + lcol) * 72 + 1 * 32 + quad * 8);
        #pragma unroll
        for (int hh = 0; hh < 2; ++hh) {
            f32x4 c = __builtin_amdgcn_mfma_f32_16x16x32_bf16(a[hh][0], b0, (f32x4)0.0f, 0, 0, 0);
            acc[hh][ct] = __builtin_amdgcn_mfma_f32_16x16x32_bf16(a[hh][1], b1, c, 0, 0, 0);
        }
    }
    __syncthreads();   // all LDS reads of sx/sw done -> safe to overlay staging tiles

    // ---- stage outputs in LDS (overlaid on sx), then write coalesced ----
    unsigned short* th = sx;
    unsigned short* ph = sx + 1024;
    unsigned short* gg = sx + 1280;
    const int ml = (w0 >> 1) + quad * 2;     // local pooled m within block, 0..31
    if (lcol < 8) {
        #pragma unroll
        for (int hh = 0; hh < 2; ++hh) {
            const int pix = hh * 64 + w0 + quad * 4;
            #pragma unroll
            for (int r = 0; r < 4; ++r)
                th[(pix + r) * 8 + lcol] = f2bf(acc[hh][0][r] * LOG2E);  // pre-scale for exp2
        }
    } else {
        #pragma unroll
        for (int r2 = 0; r2 < 2; ++r2) {
            float pe = fmaxf(fmaxf(acc[0][0][2 * r2], acc[0][0][2 * r2 + 1]),
                             fmaxf(acc[1][0][2 * r2], acc[1][0][2 * r2 + 1]));
            ph[(ml + r2) * 8 + (lcol - 8)] = f2bf(pe);
        }
    }
    #pragma unroll
    for (int ct = 1; ct < 3; ++ct) {
        const int cg = (ct - 1) * 16 + lcol;
        #pragma unroll
        for (int r2 = 0; r2 < 2; ++r2) {
            float pe = fmaxf(fmaxf(acc[0][ct][2 * r2], acc[0][ct][2 * r2 + 1]),
                             fmaxf(acc[1][ct][2 * r2], acc[1][ct][2 * r2 + 1]));
            gg[cg * 32 + ml + r2] = f2bf(pe);
        }
    }
    __syncthreads();

    // coalesced global writes: 288 float4 total (th 128, ph 32, gg 128)
    const float4* sv4 = (const float4*)sx;
    float4* th4 = (float4*)(theta_bf + ((size_t)b * NPIX + hp * 128) * 8);
    float4* ph4 = (float4*)(phi_bf + ((size_t)b * MPOOL + hp * 32) * 8);
    for (int idx = tid; idx < 288; idx += 256) {
        float4 v = sv4[idx];
        if (idx < 128) {
            th4[idx] = v;
        } else if (idx < 160) {
            ph4[idx - 128] = v;
        } else {
            const int gi = idx - 160;            // 0..127
            const int ch = gi >> 2, part = gi & 3;
            *(float4*)(gT_bf + ((size_t)b * 32 + ch) * MPOOL + hp * 32 + part * 8) = v;
        }
    }
}

// ---------------- attn v3: round-3 structure at FULL occupancy ----------------
// 256 blocks (16 b x 16 qb) x 1024 thr = 16 waves; wave = 16 q rows (per-wave code
// identical to round 3). LDS 68.5 KB -> 2 blocks/CU -> 32 waves/CU (100%) vs round-3's
// 16 (meas. 35%). sg single-buffered (prefetch in regs, write-back after barrier);
// swo removed (epilogue reads woT_bf from L2 directly). No tail barrier at t=3.
__global__ __launch_bounds__(1024) void attn_kernel(const unsigned short* __restrict__ theta_bf,
                                                    const unsigned short* __restrict__ phi_bf,
                                                    const unsigned short* __restrict__ gT_bf,
                                                    const unsigned short* __restrict__ woT_bf,
                                                    const float* __restrict__ x,
                                                    const float* __restrict__ gamma,
                                                    float* __restrict__ out) {
    __shared__ unsigned short sphi[MPOOL * 8];    // 16 KB
    __shared__ unsigned short sg[32 * 264];       // 16.9 KB: gT tile [32 ch][256 m + 8 pad]
    __shared__ unsigned short sP[16][16 * 72];    // 36.9 KB: per-wave P 16q x 64m, stride 72

    const int tid  = threadIdx.x;
    const int b    = blockIdx.x >> 4;
    const int qb   = blockIdx.x & 15;
    const int w    = tid >> 6;                    // wave 0..15
    const int lane = tid & 63;
    const int quad = lane >> 4;
    const int lcol = lane & 15;

    // stage phi[b] (16 KB): 1024 float4, one per thread
    {
        const float4* src = (const float4*)(phi_bf + (size_t)b * (MPOOL * 8));
        ((float4*)sphi)[tid] = src[tid];
    }
    // stage gT tile 0: thread (r=tid>>5, seg=tid&31) copies m seg*8..+7 (one float4)
    const unsigned short* gTb = gT_bf + (size_t)b * (32 * MPOOL);
    const int gr = tid >> 5, gseg = tid & 31;
    {
        *(float4*)(&sg[gr * 264 + gseg * 8]) =
            *(const float4*)(gTb + gr * MPOOL + gseg * 8);
    }
    // theta frag (K=8 real, zero-pad k>=8 -> quads 1-3 zero); used as B operand.
    const int q0w = qb * 256 + w * 16;
    bf16x8 tfrag = (bf16x8)(short)0;
    if (quad == 0)
        tfrag = *(const bf16x8*)(theta_bf + ((size_t)b * NPIX + q0w + lcol) * 8);
    __syncthreads();

    f32x4 olo = (f32x4)0.0f, ohi = (f32x4)0.0f;
    float ls = 0.f;
    unsigned short* sPw = sP[w];

    for (int t = 0; t < 4; ++t) {
        float4 pre;
        if (t < 3)
            pre = *(const float4*)(gTb + gr * MPOOL + (t + 1) * 256 + gseg * 8);
        for (int cb = 0; cb < 4; ++cb) {
            const int m0 = t * 256 + cb * 64;
            f32x4 s[4];
            #pragma unroll
            for (int sc = 0; sc < 4; ++sc) {
                bf16x8 pf = *(const bf16x8*)(sphi + (size_t)(m0 + sc * 16 + lcol) * 8);
                // S^T tile: D[row=m (quad*4+r within sc*16)][col=q (lcol)]
                s[sc] = __builtin_amdgcn_mfma_f32_16x16x32_bf16(pf, tfrag, (f32x4)0.0f, 0, 0, 0);
            }
            #pragma unroll
            for (int sc = 0; sc < 4; ++sc) {
                float e0 = exp2f(s[sc][0]);
                float e1 = exp2f(s[sc][1]);
                float e2 = exp2f(s[sc][2]);
                float e3 = exp2f(s[sc][3]);
                ls += (e0 + e1) + (e2 + e3);
                uint2 pk2;
                pk2.x = pack_bf16(e0, e1);
                pk2.y = pack_bf16(e2, e3);
                *(uint2*)(sPw + lcol * 72 + sc * 16 + quad * 4) = pk2;
            }
            asm volatile("s_waitcnt lgkmcnt(0)" ::: "memory");
            #pragma unroll
            for (int pkk = 0; pkk < 2; ++pkk) {
                bf16x8 afrag = *(const bf16x8*)(sPw + lcol * 72 + pkk * 32 + quad * 8);
                bf16x8 bg0 = *(const bf16x8*)(sg + lcol * 264 + cb * 64 + pkk * 32 + quad * 8);
                olo = __builtin_amdgcn_mfma_f32_16x16x32_bf16(afrag, bg0, olo, 0, 0, 0);
                bf16x8 bg1 = *(const bf16x8*)(sg + (16 + lcol) * 264 + cb * 64 + pkk * 32 + quad * 8);
                ohi = __builtin_amdgcn_mfma_f32_16x16x32_bf16(afrag, bg1, ohi, 0, 0, 0);
            }
        }
        if (t < 3) {
            __syncthreads();   // all waves done reading tile t
            *(float4*)(&sg[gr * 264 + gseg * 8]) = pre;
            __syncthreads();   // tile t+1 visible
        }
        // t == 3: no barrier — epilogue is wave-local, waves drain independently
    }

    // softmax denominator for q = lcol: sum over quads (lanes lcol+16k)
    ls += __shfl_xor(ls, 16);
    ls += __shfl_xor(ls, 32);
    const float invq = 1.0f / ls;

    // ag (UNNORMALIZED) -> per-wave LDS round-trip: [q][ch], stride 40
    #pragma unroll
    for (int r = 0; r < 4; ++r) {
        sPw[(quad * 4 + r) * 40 + lcol]      = f2bf(olo[r]);
        sPw[(quad * 4 + r) * 40 + 16 + lcol] = f2bf(ohi[r]);
    }
    asm volatile("s_waitcnt lgkmcnt(0)" ::: "memory");
    bf16x8 agf = *(const bf16x8*)(sPw + lcol * 40 + quad * 8);  // B[k=ch][n=q=lcol]

    const float gmi = gamma[0] * invq;
    const size_t pixbase = ((size_t)b * NPIX + q0w + lcol) * 64;
    #pragma unroll
    for (int ct = 0; ct < 4; ++ct) {
        // A[co][k] straight from L2 (woT is 4 KB, shared by all blocks)
        bf16x8 wa = *(const bf16x8*)(woT_bf + (ct * 16 + lcol) * 32 + quad * 8);
        f32x4 oc = __builtin_amdgcn_mfma_f32_16x16x32_bf16(wa, agf, (f32x4)0.0f, 0, 0, 0);
        const float4 xv = *(const float4*)(x + pixbase + ct * 16 + quad * 4);
        float4 ov;
        ov.x = xv.x + gmi * oc[0];
        ov.y = xv.y + gmi * oc[1];
        ov.z = xv.z + gmi * oc[2];
        ov.w = xv.w + gmi * oc[3];
        *(float4*)(out + pixbase + ct * 16 + quad * 4) = ov;
    }
}

extern "C" void kernel_launch(void* const* d_in, const int* in_sizes, int n_in,
                              void* d_out, int out_size, void* d_ws, size_t ws_size,
                              hipStream_t stream) {
    const float* x       = (const float*)d_in[0];
    const float* w_theta = (const float*)d_in[1];
    const float* u_theta = (const float*)d_in[2];
    const float* w_phi   = (const float*)d_in[3];
    const float* u_phi   = (const float*)d_in[4];
    const float* w_g     = (const float*)d_in[5];
    const float* u_g     = (const float*)d_in[6];
    const float* w_o     = (const float*)d_in[7];
    const float* u_o     = (const float*)d_in[8];
    const float* gamma   = (const float*)d_in[9];
    float* out = (float*)d_out;

    unsigned short* u16base  = (unsigned short*)d_ws;
    unsigned short* theta_bf = u16base;                  // 524288
    unsigned short* phi_bf   = u16base + 524288;         // 131072
    unsigned short* gT_bf    = u16base + 655360;         // 524288
    unsigned short* woT_bf   = u16base + 1179648;        // 2048

    conv_all_kernel<<<512, 256, 0, stream>>>(x, w_theta, u_theta, w_phi, u_phi, w_g, u_g,
                                             w_o, u_o, theta_bf, phi_bf, gT_bf, woT_bf);
    attn_kernel<<<256, 1024, 0, stream>>>(theta_bf, phi_bf, gT_bf, woT_bf, x, gamma, out);
}